// Round 3
// baseline (278.543 us; speedup 1.0000x reference)
//
#include <hip/hip_runtime.h>

#define IN_CH 128
#define OUTW  64
#define KT    32
#define RPB   128                 // rows per gemm block
#define TSTRIDE (RPB + 2)         // 130: (2k+row) bank pattern -> 2-way max (free)
#define WORDS_MAX 3200

// ---- phase 1a: per-block LDS bitmap of nodes with in-degree>0 ----
__global__ __launch_bounds__(256) void flag_parts(const int* __restrict__ col,
                                                  unsigned* __restrict__ parts,
                                                  int E, int N, int chunkE) {
    __shared__ unsigned bm[WORDS_MAX];
    const int tid = threadIdx.x;
    const int words = (N + 31) >> 5;
    for (int w = tid; w < words; w += 256) bm[w] = 0u;
    __syncthreads();
    const int e0 = blockIdx.x * chunkE;
    const int e1 = min(E, e0 + chunkE);
    for (int e = e0 + tid; e < e1; e += 256) {
        int c = col[e];
        if ((unsigned)c < (unsigned)N) atomicOr(&bm[c >> 5], 1u << (c & 31));
    }
    __syncthreads();
    unsigned* dst = parts + (size_t)blockIdx.x * words;
    for (int w = tid; w < words; w += 256) dst[w] = bm[w];
}

// ---- phase 1b: OR-merge parts -> final bitmap ----
__global__ __launch_bounds__(256) void merge_parts(const unsigned* __restrict__ parts,
                                                   unsigned* __restrict__ bitmap,
                                                   int words, int nParts) {
    int w = blockIdx.x * 256 + threadIdx.x;
    if (w >= words) return;
    unsigned acc = 0u;
    #pragma unroll 4
    for (int g = 0; g < nParts; ++g) acc |= parts[(size_t)g * words + w];
    bitmap[w] = acc;
}

// ---- phase 1 fallback (tiny ws): global atomic bitmap ----
__global__ __launch_bounds__(256) void flag_atomic(const int* __restrict__ col,
                                                   unsigned* __restrict__ bm,
                                                   int E, int N) {
    int e = blockIdx.x * blockDim.x + threadIdx.x;
    if (e < E) {
        int c = col[e];
        if ((unsigned)c < (unsigned)N) atomicOr(&bm[c >> 5], 1u << (c & 31));
    }
}

// ---- phase 2: out = (x @ W) masked by in-degree>0 ----
// 128 threads = 16 row-groups x 8 col-groups, 8x8 micro-tile.
// x tile staged K-MAJOR (transposed) so a-loads are ds_read_b128.
// W staged to LDS once (32 KB). All LDS reads b128, <=2-way banked.
__global__ __launch_bounds__(128) void gemm_mask(const float* __restrict__ x,
                                                 const float* __restrict__ W,
                                                 const unsigned* __restrict__ bitmap,
                                                 float* __restrict__ out, int N) {
    __shared__ float Wls[IN_CH * OUTW];     // 32 KB, row-major
    __shared__ float xT[KT * TSTRIDE];      // 16.25 KB, k-major

    const int tid = threadIdx.x;
    const int tx  = tid & 7;                // col group
    const int ty  = tid >> 3;               // row group 0..15
    const int c0  = tx * 8;
    const int r0  = ty * 8;
    const int rowBase = blockIdx.x * RPB;

    // load W once: 8192 floats / 128 threads = 16 float4 each, coalesced
    #pragma unroll
    for (int p = 0; p < 16; ++p) {
        int idx = p * 128 + tid;
        ((float4*)Wls)[idx] = ((const float4*)W)[idx];
    }

    float acc[64];
    #pragma unroll
    for (int i = 0; i < 64; ++i) acc[i] = 0.f;

    for (int k0 = 0; k0 < IN_CH; k0 += KT) {
        // stage x tile transposed: 128 rows x 32 k -> xT[k][row]
        #pragma unroll
        for (int p = 0; p < 8; ++p) {
            int idx = p * 128 + tid;
            int rl  = idx >> 3;             // row 0..127
            int kk  = (idx & 7) * 4;        // k offset 0..28
            int gr  = rowBase + rl;
            float4 v = make_float4(0.f, 0.f, 0.f, 0.f);
            if (gr < N) v = *(const float4*)(x + (size_t)gr * IN_CH + k0 + kk);
            xT[(kk + 0) * TSTRIDE + rl] = v.x;
            xT[(kk + 1) * TSTRIDE + rl] = v.y;
            xT[(kk + 2) * TSTRIDE + rl] = v.z;
            xT[(kk + 3) * TSTRIDE + rl] = v.w;
        }
        __syncthreads();

        #pragma unroll
        for (int k = 0; k < KT; ++k) {
            float4 a0 = *(const float4*)&xT[k * TSTRIDE + r0];
            float4 a1 = *(const float4*)&xT[k * TSTRIDE + r0 + 4];
            float4 b0 = *(const float4*)&Wls[(k0 + k) * OUTW + c0];
            float4 b1 = *(const float4*)&Wls[(k0 + k) * OUTW + c0 + 4];
            float a[8] = {a0.x, a0.y, a0.z, a0.w, a1.x, a1.y, a1.z, a1.w};
            float b[8] = {b0.x, b0.y, b0.z, b0.w, b1.x, b1.y, b1.z, b1.w};
            #pragma unroll
            for (int i = 0; i < 8; ++i)
                #pragma unroll
                for (int j = 0; j < 8; ++j)
                    acc[i * 8 + j] = fmaf(a[i], b[j], acc[i * 8 + j]);
        }
        __syncthreads();
    }

    // epilogue: one bitmap word covers rows r0..r0+7 (r0 is 8-aligned)
    unsigned mword = 0u;
    if (rowBase + r0 < N) mword = bitmap[(rowBase + r0) >> 5];
    #pragma unroll
    for (int i = 0; i < 8; ++i) {
        int row = rowBase + r0 + i;
        if (row < N) {
            float m = ((mword >> ((r0 + i) & 31)) & 1u) ? 1.f : 0.f;
            float* op = out + (size_t)row * OUTW + c0;
            *(float4*)(op)     = make_float4(acc[i*8+0]*m, acc[i*8+1]*m,
                                             acc[i*8+2]*m, acc[i*8+3]*m);
            *(float4*)(op + 4) = make_float4(acc[i*8+4]*m, acc[i*8+5]*m,
                                             acc[i*8+6]*m, acc[i*8+7]*m);
        }
    }
}

extern "C" void kernel_launch(void* const* d_in, const int* in_sizes, int n_in,
                              void* d_out, int out_size, void* d_ws, size_t ws_size,
                              hipStream_t stream) {
    const float* x  = (const float*)d_in[0];
    const int*   ei = (const int*)d_in[1];
    const float* W  = (const float*)d_in[3];
    float* out = (float*)d_out;

    const int N = in_sizes[0] / IN_CH;     // 100000
    const int E = in_sizes[1] / 2;         // 1600000
    const int* col = ei + E;               // edge_index[1]

    const int words = (N + 31) >> 5;       // 3125
    unsigned* bitmap = (unsigned*)d_ws;    // words
    unsigned* parts  = bitmap + words;     // nParts * words

    // pick largest parts count that fits the workspace
    int nParts = 0;
    for (int cand = 512; cand >= 64; cand >>= 1) {
        size_t need = (size_t)(cand + 1) * words * sizeof(unsigned);
        if (ws_size >= need) { nParts = cand; break; }
    }

    const int gemmBlocks = (N + RPB - 1) / RPB;

    if (nParts > 0 && words <= WORDS_MAX) {
        int chunkE = (E + nParts - 1) / nParts;
        flag_parts<<<nParts, 256, 0, stream>>>(col, parts, E, N, chunkE);
        merge_parts<<<(words + 255) / 256, 256, 0, stream>>>(parts, bitmap, words, nParts);
    } else {
        hipMemsetAsync(bitmap, 0, (size_t)words * sizeof(unsigned), stream);
        flag_atomic<<<(E + 255) / 256, 256, 0, stream>>>(col, bitmap, E, N);
    }
    gemm_mask<<<gemmBlocks, 128, 0, stream>>>(x, W, bitmap, out, N);
}